// Round 11
// baseline (197.218 us; speedup 1.0000x reference)
//
#include <hip/hip_runtime.h>

#define DEVFN __device__ __forceinline__

typedef __attribute__((ext_vector_type(8))) short bf16x8;
typedef __attribute__((ext_vector_type(4))) float f32x4;
typedef __attribute__((ext_vector_type(16))) float f32x16;

#define MFMA16(a, b, c) __builtin_amdgcn_mfma_f32_16x16x32_bf16(a, b, c, 0, 0, 0)
#define MFMA32(a, b, c) __builtin_amdgcn_mfma_f32_32x32x16_bf16(a, b, c, 0, 0, 0)

DEVFN unsigned short f2bf(float f) {
  union { float f; unsigned u; } v; v.f = f;
  unsigned r = v.u + 0x7FFFu + ((v.u >> 16) & 1u);
  return (unsigned short)(r >> 16);
}
DEVFN unsigned pack2bf(float a, float b) {
  return (unsigned)f2bf(a) | ((unsigned)f2bf(b) << 16);
}
DEVFN unsigned cvtpk(float lo, float hi) {
  unsigned r;
  asm("v_cvt_pk_bf16_f32 %0, %1, %2" : "=v"(r) : "v"(lo), "v"(hi));
  return r;
}
DEVFN void pl32swap(unsigned& a, unsigned& b) {
  asm("v_permlane32_swap_b32 %0, %1" : "+v"(a), "+v"(b));
}
DEVFN void gll16(const void* g, void* l) {
  __builtin_amdgcn_global_load_lds((__attribute__((address_space(1))) void*)g,
                                   (__attribute__((address_space(3))) void*)l,
                                   16, 0, 0);
}

// ---------------- precompute kernels ----------------

__global__ __launch_bounds__(256) void conv_x_k(const float* __restrict__ x,
                                                unsigned short* __restrict__ xb) {
  int i = (blockIdx.x * 256 + threadIdx.x) * 4;
  float4 v = *(const float4*)(x + i);
  uint2 u;
  u.x = pack2bf(v.x, v.y);
  u.y = pack2bf(v.z, v.w);
  *(uint2*)(xb + i) = u;
}

// WT[n][k] = (bf16) W[k][n], 64x64 tiles through LDS
__global__ __launch_bounds__(256) void transp_k(
    const float* __restrict__ Wq, const float* __restrict__ Wk,
    const float* __restrict__ Wv, const float* __restrict__ Wo,
    unsigned short* __restrict__ Tq, unsigned short* __restrict__ Tk,
    unsigned short* __restrict__ Tv, unsigned short* __restrict__ To) {
  __shared__ unsigned short t[64 * 65];
  int z = blockIdx.z;
  const float* src = (z == 0) ? Wq : (z == 1) ? Wk : (z == 2) ? Wv : Wo;
  unsigned short* dst = (z == 0) ? Tq : (z == 1) ? Tk : (z == 2) ? Tv : To;
  int k0 = blockIdx.x * 64, n0 = blockIdx.y * 64;
  int tid = threadIdx.x;
#pragma unroll
  for (int i = 0; i < 16; ++i) {
    int flat = i * 256 + tid;
    int r = flat >> 6, cc = flat & 63;
    t[cc * 65 + r] = f2bf(src[(size_t)(k0 + r) * 1024 + n0 + cc]);
  }
  __syncthreads();
#pragma unroll
  for (int i = 0; i < 16; ++i) {
    int flat = i * 256 + tid;
    int rr = flat >> 6, cc = flat & 63;
    dst[(size_t)(n0 + rr) * 1024 + k0 + cc] = t[rr * 65 + cc];
  }
}

__global__ __launch_bounds__(256) void rope_k(float2* __restrict__ rtab) {
  int idx = blockIdx.x * 256 + threadIdx.x;  // 2048*32
  int s = idx >> 5, j = idx & 31;
  float freq = expf(-0.28782313714981824f * (float)j);
  float ang = (float)s * freq;
  rtab[idx] = make_float2(sinf(ang), cosf(ang));
}

// ---------------- GEMM: C[8192,1024] = A(bf16) @ W, B given as WT[n][k] ----
// MODE 0: Q epilogue (RoPE + 0.125*log2e) -> [BH][S][64] row-major
// MODE 1: K epilogue (RoPE) -> FRAGMENT-LINEAR Kf (see R10 comment)
// MODE 2: V epilogue -> FRAGMENT-LINEAR Vf
// MODE 3: plain fp32 -> d_out
template <int MODE>
__global__ __launch_bounds__(256) void gemm_k(
    const unsigned short* __restrict__ A, const unsigned short* __restrict__ WT,
    void* __restrict__ outp, const float2* __restrict__ rtab) {
  __shared__ unsigned short At[128 * 64];
  __shared__ unsigned short Bt[128 * 64];
  const int tid = threadIdx.x;
  const int w = tid >> 6, lane = tid & 63, g = lane >> 4, c = lane & 15;
  const int wr = w >> 1, wc = w & 1;
  const int m0 = blockIdx.x * 128, n0 = blockIdx.y * 128;

  f32x4 zero = {0.f, 0.f, 0.f, 0.f};
  f32x4 acc[4][4];
#pragma unroll
  for (int i = 0; i < 4; ++i)
#pragma unroll
    for (int j = 0; j < 4; ++j) acc[i][j] = zero;

  for (int k0 = 0; k0 < 1024; k0 += 64) {
#pragma unroll
    for (int p = 0; p < 4; ++p) {
      int i = p * 256 + tid;
      int row = i >> 3, ls = i & 7;
      size_t off = ((size_t)(m0 + row) * 1024 + k0) * 2 + ((ls ^ (row & 7)) << 4);
      gll16((const char*)A + off, (char*)At + p * 4096 + w * 1024);
      size_t offb = ((size_t)(n0 + row) * 1024 + k0) * 2 + ((ls ^ (row & 7)) << 4);
      gll16((const char*)WT + offb, (char*)Bt + p * 4096 + w * 1024);
    }
    __syncthreads();
#pragma unroll
    for (int ks = 0; ks < 2; ++ks) {
      bf16x8 af[4], bfv[4];
#pragma unroll
      for (int am = 0; am < 4; ++am) {
        int row = wr * 64 + am * 16 + c;
        af[am] = *(const bf16x8*)(At + row * 64 + ((((ks << 2) | g) ^ (row & 7)) << 3));
      }
#pragma unroll
      for (int bn = 0; bn < 4; ++bn) {
        int row = wc * 64 + bn * 16 + c;
        bfv[bn] = *(const bf16x8*)(Bt + row * 64 + ((((ks << 2) | g) ^ (row & 7)) << 3));
      }
#pragma unroll
      for (int am = 0; am < 4; ++am)
#pragma unroll
        for (int bn = 0; bn < 4; ++bn)
          acc[am][bn] = MFMA16(af[am], bfv[bn], acc[am][bn]);
    }
    __syncthreads();
  }

  if (MODE == 0) {
    unsigned short* outb = (unsigned short*)outp;
#pragma unroll
    for (int am = 0; am < 4; ++am)
#pragma unroll
      for (int bp = 0; bp < 2; ++bp) {
        int col = n0 + wc * 64 + bp * 16 + c;
        int h = col >> 6, j = col & 63;
#pragma unroll
        for (int r = 0; r < 4; ++r) {
          int row = m0 + wr * 64 + am * 16 + (g << 2) + r;
          int b = row >> 11, s = row & 2047;
          float x1 = acc[am][bp][r], x2 = acc[am][bp + 2][r];
          float2 sc = rtab[s * 32 + j];
          float o1 = (sc.y * x1 - sc.x * x2) * 0.18033688011112042f;
          float o2 = (sc.x * x1 + sc.y * x2) * 0.18033688011112042f;
          size_t base = (((size_t)(b * 16 + h)) * 2048 + s) * 64;
          outb[base + j] = f2bf(o1);
          outb[base + 32 + j] = f2bf(o2);
        }
      }
  } else if (MODE == 1) {
    unsigned short* outb = (unsigned short*)outp;
#pragma unroll
    for (int am = 0; am < 4; ++am)
#pragma unroll
      for (int bp = 0; bp < 2; ++bp) {
        int col = n0 + wc * 64 + bp * 16 + c;
        int h = col >> 6, j = col & 63;  // j in [0,32)
        const int kb = j >> 4, hil = (j >> 3) & 1, el = j & 7;
#pragma unroll
        for (int r = 0; r < 4; ++r) {
          int row = m0 + wr * 64 + am * 16 + (g << 2) + r;
          int b = row >> 11, s = row & 2047;
          float x1 = acc[am][bp][r], x2 = acc[am][bp + 2][r];
          float2 sc = rtab[s * 32 + j];
          float o1 = sc.y * x1 - sc.x * x2;
          float o2 = sc.x * x1 + sc.y * x2;
          size_t base = (size_t)(b * 16 + h) * 131072 + (size_t)(s >> 5) * 2048 +
                        (hil * 32 + (s & 31)) * 8 + el;
          outb[base + kb * 512] = f2bf(o1);
          outb[base + (kb + 2) * 512] = f2bf(o2);
        }
      }
  } else if (MODE == 2) {
    unsigned short* outb = (unsigned short*)outp;
#pragma unroll
    for (int am = 0; am < 4; ++am)
#pragma unroll
      for (int bn = 0; bn < 4; ++bn) {
        int col = n0 + wc * 64 + bn * 16 + c;
        int h = col >> 6, d = col & 63;
        int row0 = m0 + wr * 64 + am * 16 + (g << 2);
        int b = row0 >> 11, s0 = row0 & 2047;
        uint2 u;
        u.x = pack2bf(acc[am][bn][0], acc[am][bn][1]);
        u.y = pack2bf(acc[am][bn][2], acc[am][bn][3]);
        size_t off = (size_t)(b * 16 + h) * 131072 + (size_t)(s0 >> 6) * 4096 +
                     ((s0 >> 4) & 3) * 1024 + (d >> 5) * 512 +
                     (((s0 >> 3) & 1) * 32 + (d & 31)) * 8 + (s0 & 7);
        *(uint2*)(outb + off) = u;
      }
  } else {
    float* outf = (float*)outp;
#pragma unroll
    for (int am = 0; am < 4; ++am)
#pragma unroll
      for (int bn = 0; bn < 4; ++bn)
#pragma unroll
        for (int r = 0; r < 4; ++r)
          outf[(size_t)(m0 + wr * 64 + am * 16 + (g << 2) + r) * 1024 +
               (n0 + wc * 64 + bn * 16 + c)] = acc[am][bn][r];
  }
}

// ---------------- flash attention (causal, split-kv, barrier-once) ---------
// Q: [BH][2048][64] bf16 (pre-scaled 0.125*log2e). Kf/Vf fragment-linear.
// 4096 UNIFORM waves (16/17 steps each): wave-pair (role 0/1) co-owns units
// (P, 63-P); role0 does first kv-halves, role1 second halves (+diagonal).
// Partials (m, l, O-bf16) merged via LDS with ONE barrier (flash split-k).
// 1024 blocks x 4 waves = 4 waves/SIMD (R10 had 2): doubles TLP over the
// ~2300cy/step exposed latency. No K-prefetch rotation (saves 32 movs/step;
// inter-wave hiding replaces it); VGPR must stay <=128 (R4 spill tripwire).
__global__ __launch_bounds__(256, 4) void attn_k(
    const unsigned short* __restrict__ Q, const unsigned short* __restrict__ Kf,
    const unsigned short* __restrict__ Vf, unsigned short* __restrict__ ctx) {
  // partials: [pair(2)][slot(3)][lane(64)][19 dwords]; stride 19 -> 2 lanes/
  // bank (free). words 0..15 = O bf16-pairs, 16 = m, 17 = l, 18 = pad.
  __shared__ unsigned smem[2 * 3 * 64 * 19];

  const int blk = blockIdx.x;               // 1024 blocks, all resident
  const int xcd = blk & 7, r = blk >> 3;
  const int bh = (xcd << 3) + (r & 7);      // 8 heads/XCD: Kf/Vf L2-resident
  const int p2 = r >> 3;                    // 0..15
  const int tid = threadIdx.x;
  const int w = tid >> 6, lane = tid & 63;
  const int hi = lane >> 5, c5 = lane & 31;
  const int P = p2 * 2 + (w >> 1);          // pair id 0..31
  const int role = w & 1;
  const int base = (w >> 1) * 3;            // LDS slot base for this pair

  const unsigned short* Qbh = Q + (size_t)bh * 2048 * 64;
  const unsigned short* Kbh = Kf + (size_t)bh * 131072;
  const unsigned short* Vbh = Vf + (size_t)bh * 131072;
  const int b = bh >> 4, h = bh & 15;

  f32x16 zacc;
#pragma unroll
  for (int i = 0; i < 16; ++i) zacc[i] = 0.f;

  // ---- process unit u over kv-steps [s0,s1); mask at st==dstp ----
  auto process = [&](int u, int s0, int s1, int dstp, float& m_run,
                     float& l_run, f32x16 (&oacc)[2]) {
    const int qw = u * 32;
    bf16x8 qf[4];
#pragma unroll
    for (int kb = 0; kb < 4; ++kb)
      qf[kb] = *(const bf16x8*)(Qbh + (size_t)(qw + c5) * 64 + kb * 16 + hi * 8);
    oacc[0] = zacc; oacc[1] = zacc;
    m_run = -1e30f; l_run = 0.f;

    for (int st = s0; st < s1; ++st) {
      // K fragments (lane-contiguous 1KB loads) + QK^T
      f32x16 sacc[2];
      const unsigned short* kbase = Kbh + (size_t)st * 4096 + lane * 8;
      __builtin_amdgcn_s_setprio(1);
#pragma unroll
      for (int t = 0; t < 2; ++t) {
        bf16x8 k0 = *(const bf16x8*)(kbase + t * 2048);
        bf16x8 k1 = *(const bf16x8*)(kbase + t * 2048 + 512);
        bf16x8 k2 = *(const bf16x8*)(kbase + t * 2048 + 1024);
        bf16x8 k3 = *(const bf16x8*)(kbase + t * 2048 + 1536);
        sacc[t] = MFMA32(k0, qf[0], zacc);
        sacc[t] = MFMA32(k1, qf[1], sacc[t]);
        sacc[t] = MFMA32(k2, qf[2], sacc[t]);
        sacc[t] = MFMA32(k3, qf[3], sacc[t]);
      }
      __builtin_amdgcn_s_setprio(0);

      // V fragments issued now; softmax+pword hide their latency (T14)
      const unsigned short* vbase = Vbh + (size_t)st * 4096 + lane * 8;
      bf16x8 vfr[2][4];
#pragma unroll
      for (int kb = 0; kb < 4; ++kb) {
        vfr[0][kb] = *(const bf16x8*)(vbase + kb * 1024);
        vfr[1][kb] = *(const bf16x8*)(vbase + kb * 1024 + 512);
      }

      // causal mask (diagonal step only)
      if (st == dstp) {
        const int q = qw + c5;
#pragma unroll
        for (int t = 0; t < 2; ++t) {
          const int kvb = st * 64 + t * 32 + (hi << 2);
#pragma unroll
          for (int i = 0; i < 16; ++i) {
            int kv = kvb + (i & 3) + ((i >> 2) << 3);
            if (kv > q) sacc[t][i] = -1e30f;
          }
        }
      }

      // online softmax (q lane-local)
      float vmax = fmaxf(sacc[0][0], sacc[0][1]);
#pragma unroll
      for (int t = 0; t < 2; ++t)
#pragma unroll
        for (int i = (t == 0 ? 2 : 0); i < 16; i += 2)
          vmax = fmaxf(vmax, fmaxf(sacc[t][i], sacc[t][i + 1]));  // v_max3
      vmax = fmaxf(vmax, __shfl_xor(vmax, 32, 64));
      if (!__all(vmax <= m_run + 8.0f)) {  // defer-max (log2 domain, THR=8)
        float m_new = fmaxf(m_run, vmax);
        float alpha = exp2f(m_run - m_new);
        l_run *= alpha;
#pragma unroll
        for (int i = 0; i < 16; ++i) {
          oacc[0][i] *= alpha;
          oacc[1][i] *= alpha;
        }
        m_run = m_new;
      }
      float psum = 0.f;
#pragma unroll
      for (int t = 0; t < 2; ++t)
#pragma unroll
        for (int i = 0; i < 16; ++i) {
          float pv = exp2f(sacc[t][i] - m_run);
          sacc[t][i] = pv;
          psum += pv;
        }
      psum += __shfl_xor(psum, 32, 64);
      l_run += psum;

      // P -> bf16 PV B-fragments: 16 cvt_pk + 8 permlane32_swap
      unsigned pword[4][4];
#pragma unroll
      for (int t = 0; t < 2; ++t) {
        unsigned X[4][2];
#pragma unroll
        for (int u2 = 0; u2 < 4; ++u2)
#pragma unroll
          for (int wp = 0; wp < 2; ++wp)
            X[u2][wp] = cvtpk(sacc[t][u2 * 4 + 2 * wp], sacc[t][u2 * 4 + 2 * wp + 1]);
#pragma unroll
        for (int par = 0; par < 2; ++par) {
          const int kb = 2 * t + par;
#pragma unroll
          for (int wp = 0; wp < 2; ++wp) {
            unsigned a = X[2 * par][wp], b2 = X[2 * par + 1][wp];
            pl32swap(a, b2);
            pword[kb][wp] = a;
            pword[kb][wp + 2] = b2;
          }
        }
      }

      // PV
      __builtin_amdgcn_s_setprio(1);
#pragma unroll
      for (int kb = 0; kb < 4; ++kb) {
        union { unsigned u[4]; bf16x8 v; } pw;
#pragma unroll
        for (int k2 = 0; k2 < 4; ++k2) pw.u[k2] = pword[kb][k2];
        oacc[0] = MFMA32(vfr[0][kb], pw.v, oacc[0]);
        oacc[1] = MFMA32(vfr[1][kb], pw.v, oacc[1]);
      }
      __builtin_amdgcn_s_setprio(0);
    }
  };

  auto store_partial = [&](int slot, const f32x16 (&o)[2], float m, float l) {
    unsigned* p = smem + ((size_t)slot * 64 + lane) * 19;
#pragma unroll
    for (int dt = 0; dt < 2; ++dt)
#pragma unroll
      for (int idx = 0; idx < 8; ++idx)
        p[dt * 8 + idx] = cvtpk(o[dt][2 * idx], o[dt][2 * idx + 1]);
    p[16] = __float_as_uint(m);
    p[17] = __float_as_uint(l);
  };

  auto bf_lo = [](unsigned u) { return __uint_as_float(u << 16); };
  auto bf_hi = [](unsigned u) { return __uint_as_float(u & 0xFFFF0000u); };

  // merge two LDS partials -> ctx rows of unit u
  auto merge_slots = [&](int s0, int s1, int u) {
    const unsigned* q0 = smem + ((size_t)s0 * 64 + lane) * 19;
    const unsigned* q1 = smem + ((size_t)s1 * 64 + lane) * 19;
    float m0 = __uint_as_float(q0[16]), l0 = __uint_as_float(q0[17]);
    float m1 = __uint_as_float(q1[16]), l1 = __uint_as_float(q1[17]);
    float m = fmaxf(m0, m1);
    float a0 = exp2f(m0 - m), a1 = exp2f(m1 - m);
    float li = 1.f / (l0 * a0 + l1 * a1);
    a0 *= li; a1 *= li;
    unsigned short* crow = ctx + ((size_t)(b * 2048 + u * 32 + c5)) * 1024 + h * 64;
#pragma unroll
    for (int dt = 0; dt < 2; ++dt)
#pragma unroll
      for (int uu = 0; uu < 4; ++uu) {
        unsigned w0a = q0[dt * 8 + 2 * uu], w1a = q1[dt * 8 + 2 * uu];
        unsigned w0b = q0[dt * 8 + 2 * uu + 1], w1b = q1[dt * 8 + 2 * uu + 1];
        uint2 o;
        o.x = cvtpk(bf_lo(w0a) * a0 + bf_lo(w1a) * a1,
                    bf_hi(w0a) * a0 + bf_hi(w1a) * a1);
        o.y = cvtpk(bf_lo(w0b) * a0 + bf_lo(w1b) * a1,
                    bf_hi(w0b) * a0 + bf_hi(w1b) * a1);
        *(uint2*)(crow + dt * 32 + 8 * uu + 4 * hi) = o;
      }
  };

  // merge register partial with one LDS partial -> ctx rows of unit u
  auto merge_reg = [&](const f32x16 (&o)[2], float m_r, float l_r, int s0, int u) {
    const unsigned* q0 = smem + ((size_t)s0 * 64 + lane) * 19;
    float m0 = __uint_as_float(q0[16]), l0 = __uint_as_float(q0[17]);
    float m = fmaxf(m0, m_r);
    float a0 = exp2f(m0 - m), ar = exp2f(m_r - m);
    float li = 1.f / (l0 * a0 + l_r * ar);
    a0 *= li; ar *= li;
    unsigned short* crow = ctx + ((size_t)(b * 2048 + u * 32 + c5)) * 1024 + h * 64;
#pragma unroll
    for (int dt = 0; dt < 2; ++dt)
#pragma unroll
      for (int uu = 0; uu < 4; ++uu) {
        unsigned w0a = q0[dt * 8 + 2 * uu];
        unsigned w0b = q0[dt * 8 + 2 * uu + 1];
        uint2 ov;
        ov.x = cvtpk(o[dt][4 * uu] * ar + bf_lo(w0a) * a0,
                     o[dt][4 * uu + 1] * ar + bf_hi(w0a) * a0);
        ov.y = cvtpk(o[dt][4 * uu + 2] * ar + bf_lo(w0b) * a0,
                     o[dt][4 * uu + 3] * ar + bf_hi(w0b) * a0);
        *(uint2*)(crow + dt * 32 + 8 * uu + 4 * hi) = ov;
      }
  };

  // ---- main: units P and V=63-P, kv split at half ----
  const int V = 63 - P;
  const int Sa = (P >> 1) + 1, Sb = (V >> 1) + 1;  // Sa+Sb = 33
  const int ha = Sa >> 1, hb = Sb >> 1;            // role0: 16 steps, role1: 17

  float m, l;
  f32x16 oacc[2];
  if (role == 0) {
    process(P, 0, ha, -1, m, l, oacc);
    store_partial(base + 0, oacc, m, l);
    process(V, 0, hb, -1, m, l, oacc);
    store_partial(base + 2, oacc, m, l);
  } else {
    process(P, ha, Sa, Sa - 1, m, l, oacc);
    store_partial(base + 1, oacc, m, l);
    process(V, hb, Sb, Sb - 1, m, l, oacc);
    // V-partial stays in registers
  }
  __syncthreads();
  if (role == 0) {
    merge_slots(base + 0, base + 1, P);
  } else {
    merge_reg(oacc, m, l, base + 2, V);
  }
}

// ---------------- launcher ----------------

extern "C" void kernel_launch(void* const* d_in, const int* in_sizes, int n_in,
                              void* d_out, int out_size, void* d_ws, size_t ws_size,
                              hipStream_t stream) {
  (void)in_sizes; (void)n_in; (void)out_size; (void)ws_size;
  const float* x = (const float*)d_in[0];
  const float* Wq = (const float*)d_in[1];
  const float* Wk = (const float*)d_in[2];
  const float* Wv = (const float*)d_in[3];
  const float* Wo = (const float*)d_in[4];
  char* ws = (char*)d_ws;
  const size_t MiB = 1024 * 1024;
  unsigned short* xb  = (unsigned short*)(ws);             // 16 MiB
  unsigned short* WTq = (unsigned short*)(ws + 16 * MiB);  // 2 MiB each
  unsigned short* WTk = (unsigned short*)(ws + 18 * MiB);
  unsigned short* WTv = (unsigned short*)(ws + 20 * MiB);
  unsigned short* WTo = (unsigned short*)(ws + 22 * MiB);
  unsigned short* Qb  = (unsigned short*)(ws + 24 * MiB);  // 16 MiB each
  unsigned short* Kfb = (unsigned short*)(ws + 40 * MiB);
  unsigned short* Vfb = (unsigned short*)(ws + 56 * MiB);
  unsigned short* ctx = (unsigned short*)(ws + 72 * MiB);
  float2* rtab = (float2*)(ws + 88 * MiB);                 // 512 KiB

  conv_x_k<<<8192, 256, 0, stream>>>(x, xb);
  transp_k<<<dim3(16, 16, 4), 256, 0, stream>>>(Wq, Wk, Wv, Wo, WTq, WTk, WTv, WTo);
  rope_k<<<256, 256, 0, stream>>>(rtab);
  gemm_k<0><<<dim3(64, 8), 256, 0, stream>>>(xb, WTq, Qb, rtab);
  gemm_k<1><<<dim3(64, 8), 256, 0, stream>>>(xb, WTk, Kfb, rtab);
  gemm_k<2><<<dim3(64, 8), 256, 0, stream>>>(xb, WTv, Vfb, rtab);
  attn_k<<<1024, 256, 0, stream>>>(Qb, Kfb, Vfb, ctx);
  gemm_k<3><<<dim3(64, 8), 256, 0, stream>>>(ctx, WTo, d_out, rtab);
}

// Round 12
// 195.299 us; speedup vs baseline: 1.0098x; 1.0098x over previous
//
#include <hip/hip_runtime.h>

#define DEVFN __device__ __forceinline__

typedef __attribute__((ext_vector_type(8))) short bf16x8;
typedef __attribute__((ext_vector_type(4))) float f32x4;
typedef __attribute__((ext_vector_type(16))) float f32x16;

#define MFMA16(a, b, c) __builtin_amdgcn_mfma_f32_16x16x32_bf16(a, b, c, 0, 0, 0)
#define MFMA32(a, b, c) __builtin_amdgcn_mfma_f32_32x32x16_bf16(a, b, c, 0, 0, 0)

DEVFN unsigned short f2bf(float f) {
  union { float f; unsigned u; } v; v.f = f;
  unsigned r = v.u + 0x7FFFu + ((v.u >> 16) & 1u);
  return (unsigned short)(r >> 16);
}
DEVFN unsigned pack2bf(float a, float b) {
  return (unsigned)f2bf(a) | ((unsigned)f2bf(b) << 16);
}
DEVFN unsigned cvtpk(float lo, float hi) {
  unsigned r;
  asm("v_cvt_pk_bf16_f32 %0, %1, %2" : "=v"(r) : "v"(lo), "v"(hi));
  return r;
}
DEVFN void pl32swap(unsigned& a, unsigned& b) {
  asm("v_permlane32_swap_b32 %0, %1" : "+v"(a), "+v"(b));
}
DEVFN void gll16(const void* g, void* l) {
  __builtin_amdgcn_global_load_lds((__attribute__((address_space(1))) void*)g,
                                   (__attribute__((address_space(3))) void*)l,
                                   16, 0, 0);
}

// ---------------- precompute kernels ----------------

__global__ __launch_bounds__(256) void conv_x_k(const float* __restrict__ x,
                                                unsigned short* __restrict__ xb) {
  int i = (blockIdx.x * 256 + threadIdx.x) * 4;
  float4 v = *(const float4*)(x + i);
  uint2 u;
  u.x = pack2bf(v.x, v.y);
  u.y = pack2bf(v.z, v.w);
  *(uint2*)(xb + i) = u;
}

// WT[n][k] = (bf16) W[k][n], 64x64 tiles through LDS
__global__ __launch_bounds__(256) void transp_k(
    const float* __restrict__ Wq, const float* __restrict__ Wk,
    const float* __restrict__ Wv, const float* __restrict__ Wo,
    unsigned short* __restrict__ Tq, unsigned short* __restrict__ Tk,
    unsigned short* __restrict__ Tv, unsigned short* __restrict__ To) {
  __shared__ unsigned short t[64 * 65];
  int z = blockIdx.z;
  const float* src = (z == 0) ? Wq : (z == 1) ? Wk : (z == 2) ? Wv : Wo;
  unsigned short* dst = (z == 0) ? Tq : (z == 1) ? Tk : (z == 2) ? Tv : To;
  int k0 = blockIdx.x * 64, n0 = blockIdx.y * 64;
  int tid = threadIdx.x;
#pragma unroll
  for (int i = 0; i < 16; ++i) {
    int flat = i * 256 + tid;
    int r = flat >> 6, cc = flat & 63;
    t[cc * 65 + r] = f2bf(src[(size_t)(k0 + r) * 1024 + n0 + cc]);
  }
  __syncthreads();
#pragma unroll
  for (int i = 0; i < 16; ++i) {
    int flat = i * 256 + tid;
    int rr = flat >> 6, cc = flat & 63;
    dst[(size_t)(n0 + rr) * 1024 + k0 + cc] = t[rr * 65 + cc];
  }
}

__global__ __launch_bounds__(256) void rope_k(float2* __restrict__ rtab) {
  int idx = blockIdx.x * 256 + threadIdx.x;  // 2048*32
  int s = idx >> 5, j = idx & 31;
  float freq = expf(-0.28782313714981824f * (float)j);
  float ang = (float)s * freq;
  rtab[idx] = make_float2(sinf(ang), cosf(ang));
}

// ---------------- GEMM: C[8192,1024] = A(bf16) @ W, B given as WT[n][k] ----
// MODE 0: Q epilogue (RoPE + 0.125*log2e) -> [BH][S][64] row-major
// MODE 1: K epilogue (RoPE) -> FRAGMENT-LINEAR Kf
// MODE 2: V epilogue -> FRAGMENT-LINEAR Vf
// MODE 3: plain fp32 -> d_out
template <int MODE>
__global__ __launch_bounds__(256) void gemm_k(
    const unsigned short* __restrict__ A, const unsigned short* __restrict__ WT,
    void* __restrict__ outp, const float2* __restrict__ rtab) {
  __shared__ unsigned short At[128 * 64];
  __shared__ unsigned short Bt[128 * 64];
  const int tid = threadIdx.x;
  const int w = tid >> 6, lane = tid & 63, g = lane >> 4, c = lane & 15;
  const int wr = w >> 1, wc = w & 1;
  const int m0 = blockIdx.x * 128, n0 = blockIdx.y * 128;

  f32x4 zero = {0.f, 0.f, 0.f, 0.f};
  f32x4 acc[4][4];
#pragma unroll
  for (int i = 0; i < 4; ++i)
#pragma unroll
    for (int j = 0; j < 4; ++j) acc[i][j] = zero;

  for (int k0 = 0; k0 < 1024; k0 += 64) {
#pragma unroll
    for (int p = 0; p < 4; ++p) {
      int i = p * 256 + tid;
      int row = i >> 3, ls = i & 7;
      size_t off = ((size_t)(m0 + row) * 1024 + k0) * 2 + ((ls ^ (row & 7)) << 4);
      gll16((const char*)A + off, (char*)At + p * 4096 + w * 1024);
      size_t offb = ((size_t)(n0 + row) * 1024 + k0) * 2 + ((ls ^ (row & 7)) << 4);
      gll16((const char*)WT + offb, (char*)Bt + p * 4096 + w * 1024);
    }
    __syncthreads();
#pragma unroll
    for (int ks = 0; ks < 2; ++ks) {
      bf16x8 af[4], bfv[4];
#pragma unroll
      for (int am = 0; am < 4; ++am) {
        int row = wr * 64 + am * 16 + c;
        af[am] = *(const bf16x8*)(At + row * 64 + ((((ks << 2) | g) ^ (row & 7)) << 3));
      }
#pragma unroll
      for (int bn = 0; bn < 4; ++bn) {
        int row = wc * 64 + bn * 16 + c;
        bfv[bn] = *(const bf16x8*)(Bt + row * 64 + ((((ks << 2) | g) ^ (row & 7)) << 3));
      }
#pragma unroll
      for (int am = 0; am < 4; ++am)
#pragma unroll
        for (int bn = 0; bn < 4; ++bn)
          acc[am][bn] = MFMA16(af[am], bfv[bn], acc[am][bn]);
    }
    __syncthreads();
  }

  if (MODE == 0) {
    unsigned short* outb = (unsigned short*)outp;
#pragma unroll
    for (int am = 0; am < 4; ++am)
#pragma unroll
      for (int bp = 0; bp < 2; ++bp) {
        int col = n0 + wc * 64 + bp * 16 + c;
        int h = col >> 6, j = col & 63;
#pragma unroll
        for (int r = 0; r < 4; ++r) {
          int row = m0 + wr * 64 + am * 16 + (g << 2) + r;
          int b = row >> 11, s = row & 2047;
          float x1 = acc[am][bp][r], x2 = acc[am][bp + 2][r];
          float2 sc = rtab[s * 32 + j];
          float o1 = (sc.y * x1 - sc.x * x2) * 0.18033688011112042f;
          float o2 = (sc.x * x1 + sc.y * x2) * 0.18033688011112042f;
          size_t base = (((size_t)(b * 16 + h)) * 2048 + s) * 64;
          outb[base + j] = f2bf(o1);
          outb[base + 32 + j] = f2bf(o2);
        }
      }
  } else if (MODE == 1) {
    unsigned short* outb = (unsigned short*)outp;
#pragma unroll
    for (int am = 0; am < 4; ++am)
#pragma unroll
      for (int bp = 0; bp < 2; ++bp) {
        int col = n0 + wc * 64 + bp * 16 + c;
        int h = col >> 6, j = col & 63;  // j in [0,32)
        const int kb = j >> 4, hil = (j >> 3) & 1, el = j & 7;
#pragma unroll
        for (int r = 0; r < 4; ++r) {
          int row = m0 + wr * 64 + am * 16 + (g << 2) + r;
          int b = row >> 11, s = row & 2047;
          float x1 = acc[am][bp][r], x2 = acc[am][bp + 2][r];
          float2 sc = rtab[s * 32 + j];
          float o1 = sc.y * x1 - sc.x * x2;
          float o2 = sc.x * x1 + sc.y * x2;
          size_t base = (size_t)(b * 16 + h) * 131072 + (size_t)(s >> 5) * 2048 +
                        (hil * 32 + (s & 31)) * 8 + el;
          outb[base + kb * 512] = f2bf(o1);
          outb[base + (kb + 2) * 512] = f2bf(o2);
        }
      }
  } else if (MODE == 2) {
    unsigned short* outb = (unsigned short*)outp;
#pragma unroll
    for (int am = 0; am < 4; ++am)
#pragma unroll
      for (int bn = 0; bn < 4; ++bn) {
        int col = n0 + wc * 64 + bn * 16 + c;
        int h = col >> 6, d = col & 63;
        int row0 = m0 + wr * 64 + am * 16 + (g << 2);
        int b = row0 >> 11, s0 = row0 & 2047;
        uint2 u;
        u.x = pack2bf(acc[am][bn][0], acc[am][bn][1]);
        u.y = pack2bf(acc[am][bn][2], acc[am][bn][3]);
        size_t off = (size_t)(b * 16 + h) * 131072 + (size_t)(s0 >> 6) * 4096 +
                     ((s0 >> 4) & 3) * 1024 + (d >> 5) * 512 +
                     (((s0 >> 3) & 1) * 32 + (d & 31)) * 8 + (s0 & 7);
        *(uint2*)(outb + off) = u;
      }
  } else {
    float* outf = (float*)outp;
#pragma unroll
    for (int am = 0; am < 4; ++am)
#pragma unroll
      for (int bn = 0; bn < 4; ++bn)
#pragma unroll
        for (int r = 0; r < 4; ++r)
          outf[(size_t)(m0 + wr * 64 + am * 16 + (g << 2) + r) * 1024 +
               (n0 + wc * 64 + bn * 16 + c)] = acc[am][bn][r];
  }
}

// ---------------- flash attention (causal, even/odd split-kv) --------------
// Q: [BH][2048][64] bf16 (pre-scaled 0.125*log2e). Kf/Vf fragment-linear.
// 4096 uniform waves: pair (role 0/1) co-owns units (P, 63-P); role r does
// kv-steps {r, r+2, r+4, ...} of BOTH units -> every wave starts at st<=1
// and walks the head's K/V stream in phase (R10's range-halving broke L2
// temporal locality: FETCH 33->125MB, HBM-latency on critical path).
// Partials merged via LDS, ONE barrier. 17/16 steps per role -- uniform.
__global__ __launch_bounds__(256, 4) void attn_k(
    const unsigned short* __restrict__ Q, const unsigned short* __restrict__ Kf,
    const unsigned short* __restrict__ Vf, unsigned short* __restrict__ ctx) {
  // partials: [pair(2)][slot(3)][lane(64)][19 dwords]; stride 19 -> 2 lanes/
  // bank (free). words 0..15 = O bf16-pairs, 16 = m, 17 = l, 18 = pad.
  __shared__ unsigned smem[2 * 3 * 64 * 19];

  const int blk = blockIdx.x;               // 1024 blocks, all resident
  const int xcd = blk & 7, r = blk >> 3;
  const int bh = (xcd << 3) + (r & 7);      // 8 heads/XCD: Kf/Vf L2-resident
  const int p2 = r >> 3;                    // 0..15
  const int tid = threadIdx.x;
  const int w = tid >> 6, lane = tid & 63;
  const int hi = lane >> 5, c5 = lane & 31;
  const int P = p2 * 2 + (w >> 1);          // pair id 0..31
  const int role = w & 1;
  const int base = (w >> 1) * 3;            // LDS slot base for this pair

  const unsigned short* Qbh = Q + (size_t)bh * 2048 * 64;
  const unsigned short* Kbh = Kf + (size_t)bh * 131072;
  const unsigned short* Vbh = Vf + (size_t)bh * 131072;
  const int b = bh >> 4, h = bh & 15;

  f32x16 zacc;
#pragma unroll
  for (int i = 0; i < 16; ++i) zacc[i] = 0.f;

  // ---- process unit u, steps {role, role+2, ...} < S; mask at st==dstp ----
  auto process = [&](int u, int S, int dstp, float& m_run, float& l_run,
                     f32x16 (&oacc)[2]) {
    const int qw = u * 32;
    bf16x8 qf[4];
#pragma unroll
    for (int kb = 0; kb < 4; ++kb)
      qf[kb] = *(const bf16x8*)(Qbh + (size_t)(qw + c5) * 64 + kb * 16 + hi * 8);
    oacc[0] = zacc; oacc[1] = zacc;
    m_run = -1e30f; l_run = 0.f;

    for (int st = role; st < S; st += 2) {
      // K fragments (lane-contiguous 1KB loads) + QK^T
      f32x16 sacc[2];
      const unsigned short* kbase = Kbh + (size_t)st * 4096 + lane * 8;
      __builtin_amdgcn_s_setprio(1);
#pragma unroll
      for (int t = 0; t < 2; ++t) {
        bf16x8 k0 = *(const bf16x8*)(kbase + t * 2048);
        bf16x8 k1 = *(const bf16x8*)(kbase + t * 2048 + 512);
        bf16x8 k2 = *(const bf16x8*)(kbase + t * 2048 + 1024);
        bf16x8 k3 = *(const bf16x8*)(kbase + t * 2048 + 1536);
        sacc[t] = MFMA32(k0, qf[0], zacc);
        sacc[t] = MFMA32(k1, qf[1], sacc[t]);
        sacc[t] = MFMA32(k2, qf[2], sacc[t]);
        sacc[t] = MFMA32(k3, qf[3], sacc[t]);
      }
      __builtin_amdgcn_s_setprio(0);

      // V fragments issued now; softmax+pword hide their latency (T14)
      const unsigned short* vbase = Vbh + (size_t)st * 4096 + lane * 8;
      bf16x8 vfr[2][4];
#pragma unroll
      for (int kb = 0; kb < 4; ++kb) {
        vfr[0][kb] = *(const bf16x8*)(vbase + kb * 1024);
        vfr[1][kb] = *(const bf16x8*)(vbase + kb * 1024 + 512);
      }

      // causal mask (diagonal step only)
      if (st == dstp) {
        const int q = qw + c5;
#pragma unroll
        for (int t = 0; t < 2; ++t) {
          const int kvb = st * 64 + t * 32 + (hi << 2);
#pragma unroll
          for (int i = 0; i < 16; ++i) {
            int kv = kvb + (i & 3) + ((i >> 2) << 3);
            if (kv > q) sacc[t][i] = -1e30f;
          }
        }
      }

      // online softmax (q lane-local)
      float vmax = fmaxf(sacc[0][0], sacc[0][1]);
#pragma unroll
      for (int t = 0; t < 2; ++t)
#pragma unroll
        for (int i = (t == 0 ? 2 : 0); i < 16; i += 2)
          vmax = fmaxf(vmax, fmaxf(sacc[t][i], sacc[t][i + 1]));  // v_max3
      vmax = fmaxf(vmax, __shfl_xor(vmax, 32, 64));
      if (!__all(vmax <= m_run + 8.0f)) {  // defer-max (log2 domain, THR=8)
        float m_new = fmaxf(m_run, vmax);
        float alpha = exp2f(m_run - m_new);
        l_run *= alpha;
#pragma unroll
        for (int i = 0; i < 16; ++i) {
          oacc[0][i] *= alpha;
          oacc[1][i] *= alpha;
        }
        m_run = m_new;
      }
      float psum = 0.f;
#pragma unroll
      for (int t = 0; t < 2; ++t)
#pragma unroll
        for (int i = 0; i < 16; ++i) {
          float pv = exp2f(sacc[t][i] - m_run);
          sacc[t][i] = pv;
          psum += pv;
        }
      psum += __shfl_xor(psum, 32, 64);
      l_run += psum;

      // P -> bf16 PV B-fragments: 16 cvt_pk + 8 permlane32_swap
      unsigned pword[4][4];
#pragma unroll
      for (int t = 0; t < 2; ++t) {
        unsigned X[4][2];
#pragma unroll
        for (int u2 = 0; u2 < 4; ++u2)
#pragma unroll
          for (int wp = 0; wp < 2; ++wp)
            X[u2][wp] = cvtpk(sacc[t][u2 * 4 + 2 * wp], sacc[t][u2 * 4 + 2 * wp + 1]);
#pragma unroll
        for (int par = 0; par < 2; ++par) {
          const int kb = 2 * t + par;
#pragma unroll
          for (int wp = 0; wp < 2; ++wp) {
            unsigned a = X[2 * par][wp], b2 = X[2 * par + 1][wp];
            pl32swap(a, b2);
            pword[kb][wp] = a;
            pword[kb][wp + 2] = b2;
          }
        }
      }

      // PV
      __builtin_amdgcn_s_setprio(1);
#pragma unroll
      for (int kb = 0; kb < 4; ++kb) {
        union { unsigned u[4]; bf16x8 v; } pw;
#pragma unroll
        for (int k2 = 0; k2 < 4; ++k2) pw.u[k2] = pword[kb][k2];
        oacc[0] = MFMA32(vfr[0][kb], pw.v, oacc[0]);
        oacc[1] = MFMA32(vfr[1][kb], pw.v, oacc[1]);
      }
      __builtin_amdgcn_s_setprio(0);
    }
  };

  auto store_partial = [&](int slot, const f32x16 (&o)[2], float m, float l) {
    unsigned* p = smem + ((size_t)slot * 64 + lane) * 19;
#pragma unroll
    for (int dt = 0; dt < 2; ++dt)
#pragma unroll
      for (int idx = 0; idx < 8; ++idx)
        p[dt * 8 + idx] = cvtpk(o[dt][2 * idx], o[dt][2 * idx + 1]);
    p[16] = __float_as_uint(m);
    p[17] = __float_as_uint(l);
  };

  auto bf_lo = [](unsigned u) { return __uint_as_float(u << 16); };
  auto bf_hi = [](unsigned u) { return __uint_as_float(u & 0xFFFF0000u); };

  // merge two LDS partials -> ctx rows of unit u
  auto merge_slots = [&](int s0, int s1, int u) {
    const unsigned* q0 = smem + ((size_t)s0 * 64 + lane) * 19;
    const unsigned* q1 = smem + ((size_t)s1 * 64 + lane) * 19;
    float m0 = __uint_as_float(q0[16]), l0 = __uint_as_float(q0[17]);
    float m1 = __uint_as_float(q1[16]), l1 = __uint_as_float(q1[17]);
    float m = fmaxf(m0, m1);
    float a0 = exp2f(m0 - m), a1 = exp2f(m1 - m);
    float li = 1.f / (l0 * a0 + l1 * a1);
    a0 *= li; a1 *= li;
    unsigned short* crow = ctx + ((size_t)(b * 2048 + u * 32 + c5)) * 1024 + h * 64;
#pragma unroll
    for (int dt = 0; dt < 2; ++dt)
#pragma unroll
      for (int uu = 0; uu < 4; ++uu) {
        unsigned w0a = q0[dt * 8 + 2 * uu], w1a = q1[dt * 8 + 2 * uu];
        unsigned w0b = q0[dt * 8 + 2 * uu + 1], w1b = q1[dt * 8 + 2 * uu + 1];
        uint2 o;
        o.x = cvtpk(bf_lo(w0a) * a0 + bf_lo(w1a) * a1,
                    bf_hi(w0a) * a0 + bf_hi(w1a) * a1);
        o.y = cvtpk(bf_lo(w0b) * a0 + bf_lo(w1b) * a1,
                    bf_hi(w0b) * a0 + bf_hi(w1b) * a1);
        *(uint2*)(crow + dt * 32 + 8 * uu + 4 * hi) = o;
      }
  };

  // merge register partial with one LDS partial -> ctx rows of unit u
  auto merge_reg = [&](const f32x16 (&o)[2], float m_r, float l_r, int s0, int u) {
    const unsigned* q0 = smem + ((size_t)s0 * 64 + lane) * 19;
    float m0 = __uint_as_float(q0[16]), l0 = __uint_as_float(q0[17]);
    float m = fmaxf(m0, m_r);
    float a0 = exp2f(m0 - m), ar = exp2f(m_r - m);
    float li = 1.f / (l0 * a0 + l_r * ar);
    a0 *= li; ar *= li;
    unsigned short* crow = ctx + ((size_t)(b * 2048 + u * 32 + c5)) * 1024 + h * 64;
#pragma unroll
    for (int dt = 0; dt < 2; ++dt)
#pragma unroll
      for (int uu = 0; uu < 4; ++uu) {
        unsigned w0a = q0[dt * 8 + 2 * uu];
        unsigned w0b = q0[dt * 8 + 2 * uu + 1];
        uint2 ov;
        ov.x = cvtpk(o[dt][4 * uu] * ar + bf_lo(w0a) * a0,
                     o[dt][4 * uu + 1] * ar + bf_hi(w0a) * a0);
        ov.y = cvtpk(o[dt][4 * uu + 2] * ar + bf_lo(w0b) * a0,
                     o[dt][4 * uu + 3] * ar + bf_hi(w0b) * a0);
        *(uint2*)(crow + dt * 32 + 8 * uu + 4 * hi) = ov;
      }
  };

  // ---- main: units P and V=63-P; role r does steps {r, r+2, ...} ----
  const int V = 63 - P;
  const int Sa = (P >> 1) + 1, Sb = (V >> 1) + 1;  // Sa+Sb = 33
  const int dA = (((Sa - 1) & 1) == role) ? (Sa - 1) : -1;
  const int dB = (((Sb - 1) & 1) == role) ? (Sb - 1) : -1;

  float m, l;
  f32x16 oacc[2];
  if (role == 0) {
    process(P, Sa, dA, m, l, oacc);
    store_partial(base + 0, oacc, m, l);
    process(V, Sb, dB, m, l, oacc);
    store_partial(base + 2, oacc, m, l);
  } else {
    process(P, Sa, dA, m, l, oacc);
    store_partial(base + 1, oacc, m, l);
    process(V, Sb, dB, m, l, oacc);
    // V-partial stays in registers
  }
  __syncthreads();
  if (role == 0) {
    merge_slots(base + 0, base + 1, P);
  } else {
    merge_reg(oacc, m, l, base + 2, V);
  }
}

// ---------------- launcher ----------------

extern "C" void kernel_launch(void* const* d_in, const int* in_sizes, int n_in,
                              void* d_out, int out_size, void* d_ws, size_t ws_size,
                              hipStream_t stream) {
  (void)in_sizes; (void)n_in; (void)out_size; (void)ws_size;
  const float* x = (const float*)d_in[0];
  const float* Wq = (const float*)d_in[1];
  const float* Wk = (const float*)d_in[2];
  const float* Wv = (const float*)d_in[3];
  const float* Wo = (const float*)d_in[4];
  char* ws = (char*)d_ws;
  const size_t MiB = 1024 * 1024;
  unsigned short* xb  = (unsigned short*)(ws);             // 16 MiB
  unsigned short* WTq = (unsigned short*)(ws + 16 * MiB);  // 2 MiB each
  unsigned short* WTk = (unsigned short*)(ws + 18 * MiB);
  unsigned short* WTv = (unsigned short*)(ws + 20 * MiB);
  unsigned short* WTo = (unsigned short*)(ws + 22 * MiB);
  unsigned short* Qb  = (unsigned short*)(ws + 24 * MiB);  // 16 MiB each
  unsigned short* Kfb = (unsigned short*)(ws + 40 * MiB);
  unsigned short* Vfb = (unsigned short*)(ws + 56 * MiB);
  unsigned short* ctx = (unsigned short*)(ws + 72 * MiB);
  float2* rtab = (float2*)(ws + 88 * MiB);                 // 512 KiB

  conv_x_k<<<8192, 256, 0, stream>>>(x, xb);
  transp_k<<<dim3(16, 16, 4), 256, 0, stream>>>(Wq, Wk, Wv, Wo, WTq, WTk, WTv, WTo);
  rope_k<<<256, 256, 0, stream>>>(rtab);
  gemm_k<0><<<dim3(64, 8), 256, 0, stream>>>(xb, WTq, Qb, rtab);
  gemm_k<1><<<dim3(64, 8), 256, 0, stream>>>(xb, WTk, Kfb, rtab);
  gemm_k<2><<<dim3(64, 8), 256, 0, stream>>>(xb, WTv, Vfb, rtab);
  attn_k<<<1024, 256, 0, stream>>>(Qb, Kfb, Vfb, ctx);
  gemm_k<3><<<dim3(64, 8), 256, 0, stream>>>(ctx, WTo, d_out, rtab);
}

// Round 13
// 184.421 us; speedup vs baseline: 1.0694x; 1.0590x over previous
//
#include <hip/hip_runtime.h>

#define DEVFN __device__ __forceinline__

typedef __attribute__((ext_vector_type(8))) short bf16x8;
typedef __attribute__((ext_vector_type(4))) float f32x4;
typedef __attribute__((ext_vector_type(16))) float f32x16;

#define MFMA16(a, b, c) __builtin_amdgcn_mfma_f32_16x16x32_bf16(a, b, c, 0, 0, 0)
#define MFMA32(a, b, c) __builtin_amdgcn_mfma_f32_32x32x16_bf16(a, b, c, 0, 0, 0)

DEVFN unsigned short f2bf(float f) {
  union { float f; unsigned u; } v; v.f = f;
  unsigned r = v.u + 0x7FFFu + ((v.u >> 16) & 1u);
  return (unsigned short)(r >> 16);
}
DEVFN unsigned pack2bf(float a, float b) {
  return (unsigned)f2bf(a) | ((unsigned)f2bf(b) << 16);
}
DEVFN unsigned cvtpk(float lo, float hi) {
  unsigned r;
  asm("v_cvt_pk_bf16_f32 %0, %1, %2" : "=v"(r) : "v"(lo), "v"(hi));
  return r;
}
DEVFN void pl32swap(unsigned& a, unsigned& b) {
  asm("v_permlane32_swap_b32 %0, %1" : "+v"(a), "+v"(b));
}
DEVFN void gll16(const void* g, void* l) {
  __builtin_amdgcn_global_load_lds((__attribute__((address_space(1))) void*)g,
                                   (__attribute__((address_space(3))) void*)l,
                                   16, 0, 0);
}

// ---------------- precompute kernels ----------------

__global__ __launch_bounds__(256) void conv_x_k(const float* __restrict__ x,
                                                unsigned short* __restrict__ xb) {
  int i = (blockIdx.x * 256 + threadIdx.x) * 4;
  float4 v = *(const float4*)(x + i);
  uint2 u;
  u.x = pack2bf(v.x, v.y);
  u.y = pack2bf(v.z, v.w);
  *(uint2*)(xb + i) = u;
}

// WT[n][k] = (bf16) W[k][n], 64x64 tiles through LDS
__global__ __launch_bounds__(256) void transp_k(
    const float* __restrict__ Wq, const float* __restrict__ Wk,
    const float* __restrict__ Wv, const float* __restrict__ Wo,
    unsigned short* __restrict__ Tq, unsigned short* __restrict__ Tk,
    unsigned short* __restrict__ Tv, unsigned short* __restrict__ To) {
  __shared__ unsigned short t[64 * 65];
  int z = blockIdx.z;
  const float* src = (z == 0) ? Wq : (z == 1) ? Wk : (z == 2) ? Wv : Wo;
  unsigned short* dst = (z == 0) ? Tq : (z == 1) ? Tk : (z == 2) ? Tv : To;
  int k0 = blockIdx.x * 64, n0 = blockIdx.y * 64;
  int tid = threadIdx.x;
#pragma unroll
  for (int i = 0; i < 16; ++i) {
    int flat = i * 256 + tid;
    int r = flat >> 6, cc = flat & 63;
    t[cc * 65 + r] = f2bf(src[(size_t)(k0 + r) * 1024 + n0 + cc]);
  }
  __syncthreads();
#pragma unroll
  for (int i = 0; i < 16; ++i) {
    int flat = i * 256 + tid;
    int rr = flat >> 6, cc = flat & 63;
    dst[(size_t)(n0 + rr) * 1024 + k0 + cc] = t[rr * 65 + cc];
  }
}

__global__ __launch_bounds__(256) void rope_k(float2* __restrict__ rtab) {
  int idx = blockIdx.x * 256 + threadIdx.x;  // 2048*32
  int s = idx >> 5, j = idx & 31;
  float freq = expf(-0.28782313714981824f * (float)j);
  float ang = (float)s * freq;
  rtab[idx] = make_float2(sinf(ang), cosf(ang));
}

// ---------------- GEMM: C[8192,1024] = A(bf16) @ W, B given as WT[n][k] ----
// MODE 0: Q epilogue (RoPE + 0.125*log2e) -> [BH][S][64] row-major
// MODE 1: K epilogue (RoPE) -> FRAGMENT-LINEAR Kf
// MODE 2: V epilogue -> FRAGMENT-LINEAR Vf
// MODE 3: plain fp32 -> d_out
template <int MODE>
__global__ __launch_bounds__(256) void gemm_k(
    const unsigned short* __restrict__ A, const unsigned short* __restrict__ WT,
    void* __restrict__ outp, const float2* __restrict__ rtab) {
  __shared__ unsigned short At[128 * 64];
  __shared__ unsigned short Bt[128 * 64];
  const int tid = threadIdx.x;
  const int w = tid >> 6, lane = tid & 63, g = lane >> 4, c = lane & 15;
  const int wr = w >> 1, wc = w & 1;
  const int m0 = blockIdx.x * 128, n0 = blockIdx.y * 128;

  f32x4 zero = {0.f, 0.f, 0.f, 0.f};
  f32x4 acc[4][4];
#pragma unroll
  for (int i = 0; i < 4; ++i)
#pragma unroll
    for (int j = 0; j < 4; ++j) acc[i][j] = zero;

  for (int k0 = 0; k0 < 1024; k0 += 64) {
#pragma unroll
    for (int p = 0; p < 4; ++p) {
      int i = p * 256 + tid;
      int row = i >> 3, ls = i & 7;
      size_t off = ((size_t)(m0 + row) * 1024 + k0) * 2 + ((ls ^ (row & 7)) << 4);
      gll16((const char*)A + off, (char*)At + p * 4096 + w * 1024);
      size_t offb = ((size_t)(n0 + row) * 1024 + k0) * 2 + ((ls ^ (row & 7)) << 4);
      gll16((const char*)WT + offb, (char*)Bt + p * 4096 + w * 1024);
    }
    __syncthreads();
#pragma unroll
    for (int ks = 0; ks < 2; ++ks) {
      bf16x8 af[4], bfv[4];
#pragma unroll
      for (int am = 0; am < 4; ++am) {
        int row = wr * 64 + am * 16 + c;
        af[am] = *(const bf16x8*)(At + row * 64 + ((((ks << 2) | g) ^ (row & 7)) << 3));
      }
#pragma unroll
      for (int bn = 0; bn < 4; ++bn) {
        int row = wc * 64 + bn * 16 + c;
        bfv[bn] = *(const bf16x8*)(Bt + row * 64 + ((((ks << 2) | g) ^ (row & 7)) << 3));
      }
#pragma unroll
      for (int am = 0; am < 4; ++am)
#pragma unroll
        for (int bn = 0; bn < 4; ++bn)
          acc[am][bn] = MFMA16(af[am], bfv[bn], acc[am][bn]);
    }
    __syncthreads();
  }

  if (MODE == 0) {
    unsigned short* outb = (unsigned short*)outp;
#pragma unroll
    for (int am = 0; am < 4; ++am)
#pragma unroll
      for (int bp = 0; bp < 2; ++bp) {
        int col = n0 + wc * 64 + bp * 16 + c;
        int h = col >> 6, j = col & 63;
#pragma unroll
        for (int r = 0; r < 4; ++r) {
          int row = m0 + wr * 64 + am * 16 + (g << 2) + r;
          int b = row >> 11, s = row & 2047;
          float x1 = acc[am][bp][r], x2 = acc[am][bp + 2][r];
          float2 sc = rtab[s * 32 + j];
          float o1 = (sc.y * x1 - sc.x * x2) * 0.18033688011112042f;
          float o2 = (sc.x * x1 + sc.y * x2) * 0.18033688011112042f;
          size_t base = (((size_t)(b * 16 + h)) * 2048 + s) * 64;
          outb[base + j] = f2bf(o1);
          outb[base + 32 + j] = f2bf(o2);
        }
      }
  } else if (MODE == 1) {
    unsigned short* outb = (unsigned short*)outp;
#pragma unroll
    for (int am = 0; am < 4; ++am)
#pragma unroll
      for (int bp = 0; bp < 2; ++bp) {
        int col = n0 + wc * 64 + bp * 16 + c;
        int h = col >> 6, j = col & 63;  // j in [0,32)
        const int kb = j >> 4, hil = (j >> 3) & 1, el = j & 7;
#pragma unroll
        for (int r = 0; r < 4; ++r) {
          int row = m0 + wr * 64 + am * 16 + (g << 2) + r;
          int b = row >> 11, s = row & 2047;
          float x1 = acc[am][bp][r], x2 = acc[am][bp + 2][r];
          float2 sc = rtab[s * 32 + j];
          float o1 = sc.y * x1 - sc.x * x2;
          float o2 = sc.x * x1 + sc.y * x2;
          size_t base = (size_t)(b * 16 + h) * 131072 + (size_t)(s >> 5) * 2048 +
                        (hil * 32 + (s & 31)) * 8 + el;
          outb[base + kb * 512] = f2bf(o1);
          outb[base + (kb + 2) * 512] = f2bf(o2);
        }
      }
  } else if (MODE == 2) {
    unsigned short* outb = (unsigned short*)outp;
#pragma unroll
    for (int am = 0; am < 4; ++am)
#pragma unroll
      for (int bn = 0; bn < 4; ++bn) {
        int col = n0 + wc * 64 + bn * 16 + c;
        int h = col >> 6, d = col & 63;
        int row0 = m0 + wr * 64 + am * 16 + (g << 2);
        int b = row0 >> 11, s0 = row0 & 2047;
        uint2 u;
        u.x = pack2bf(acc[am][bn][0], acc[am][bn][1]);
        u.y = pack2bf(acc[am][bn][2], acc[am][bn][3]);
        size_t off = (size_t)(b * 16 + h) * 131072 + (size_t)(s0 >> 6) * 4096 +
                     ((s0 >> 4) & 3) * 1024 + (d >> 5) * 512 +
                     (((s0 >> 3) & 1) * 32 + (d & 31)) * 8 + (s0 & 7);
        *(uint2*)(outb + off) = u;
      }
  } else {
    float* outf = (float*)outp;
#pragma unroll
    for (int am = 0; am < 4; ++am)
#pragma unroll
      for (int bn = 0; bn < 4; ++bn)
#pragma unroll
        for (int r = 0; r < 4; ++r)
          outf[(size_t)(m0 + wr * 64 + am * 16 + (g << 2) + r) * 1024 +
               (n0 + wc * 64 + bn * 16 + c)] = acc[am][bn][r];
  }
}

// ---------------- flash attention (causal, barrier-free, frag-linear) ------
// R9 structure (validated 82us, FETCH=compulsory 33MB): 512 blocks, wave =
// 32 q-rows, autonomous, units P then 63-P (33 steps, zero tail), all waves
// phase-aligned from st=0 (split-kv variants R10/R11 broke L2 locality:
// FETCH 82-125MB, regressed). NEW vs R9: K AND V ping-pong double-buffered
// via manual 2-unrolled loop -- V(st+1) issued during step st gets a full
// iteration of latency cover (was ~300cy same-step), and static buffer
// alternation removes the 32 v_mov/step rotation. All buffer indices
// compile-time (rule #20). ~180 arch VGPR at 2 waves/SIMD (budget 256).
__global__ __launch_bounds__(256, 2) void attn_k(
    const unsigned short* __restrict__ Q, const unsigned short* __restrict__ Kf,
    const unsigned short* __restrict__ Vf, unsigned short* __restrict__ ctx) {
  const int blk = blockIdx.x;               // 512 blocks
  const int xcd = blk & 7, idx = blk >> 3;  // 8 heads/XCD: K/V L2-resident
  const int bh = (xcd << 3) + (idx & 7);
  const int pbase = (idx >> 3) << 2;
  const int tid = threadIdx.x;
  const int w = tid >> 6, lane = tid & 63;
  const int hi = lane >> 5, c5 = lane & 31;
  const int P = pbase + w;  // 0..31; wave does units P and 63-P

  const unsigned short* Qbh = Q + (size_t)bh * 2048 * 64;
  const unsigned short* Kbh = Kf + (size_t)bh * 131072;
  const unsigned short* Vbh = Vf + (size_t)bh * 131072;
  const int b = bh >> 4, h = bh & 15;

  f32x16 zacc;
#pragma unroll
  for (int i = 0; i < 16; ++i) zacc[i] = 0.f;

  auto pass = [&](int U) {
    const int qw = U * 32;
    const int S = (U >> 1) + 1;  // steps 0..S-1; diagonal at S-1

    bf16x8 qf[4];
#pragma unroll
    for (int kb = 0; kb < 4; ++kb)
      qf[kb] = *(const bf16x8*)(Qbh + (size_t)(qw + c5) * 64 + kb * 16 + hi * 8);

    f32x16 oacc[2];
    oacc[0] = zacc; oacc[1] = zacc;
    float m_run = -1e30f, l_run = 0.f;

    bf16x8 kfA[2][4], vfA[2][4], kfB[2][4], vfB[2][4];

    auto loadK = [&](int st, bf16x8 (&dst)[2][4]) {
      const unsigned short* kb_ = Kbh + (size_t)st * 4096 + lane * 8;
#pragma unroll
      for (int t = 0; t < 2; ++t)
#pragma unroll
        for (int kb = 0; kb < 4; ++kb)
          dst[t][kb] = *(const bf16x8*)(kb_ + t * 2048 + kb * 512);
    };
    auto loadV = [&](int st, bf16x8 (&dst)[2][4]) {
      const unsigned short* vb_ = Vbh + (size_t)st * 4096 + lane * 8;
#pragma unroll
      for (int kb = 0; kb < 4; ++kb) {
        dst[0][kb] = *(const bf16x8*)(vb_ + kb * 1024);
        dst[1][kb] = *(const bf16x8*)(vb_ + kb * 1024 + 512);
      }
    };

    // one kv-step: compute from Cur buffers, prefetch st+1 into Nxt
    auto step = [&](int st, bf16x8 (&kfC)[2][4], bf16x8 (&vfC)[2][4],
                    bf16x8 (&kfN)[2][4], bf16x8 (&vfN)[2][4]) {
      // ---- QK^T ----
      f32x16 sacc[2];
      __builtin_amdgcn_s_setprio(1);
#pragma unroll
      for (int t = 0; t < 2; ++t) {
        sacc[t] = MFMA32(kfC[t][0], qf[0], zacc);
#pragma unroll
        for (int kb = 1; kb < 4; ++kb)
          sacc[t] = MFMA32(kfC[t][kb], qf[kb], sacc[t]);
      }
      __builtin_amdgcn_s_setprio(0);

      // ---- prefetch next step's K and V (full iteration of cover) ----
      if (st + 1 < S) {
        loadK(st + 1, kfN);
        loadV(st + 1, vfN);
      }

      // ---- causal mask (diagonal step only) ----
      if (st == S - 1) {
        const int q = qw + c5;
#pragma unroll
        for (int t = 0; t < 2; ++t) {
          const int kvb = st * 64 + t * 32 + (hi << 2);
#pragma unroll
          for (int i = 0; i < 16; ++i) {
            int kv = kvb + (i & 3) + ((i >> 2) << 3);
            if (kv > q) sacc[t][i] = -1e30f;
          }
        }
      }

      // ---- online softmax (q lane-local) ----
      float vmax = fmaxf(sacc[0][0], sacc[0][1]);
#pragma unroll
      for (int t = 0; t < 2; ++t)
#pragma unroll
        for (int i = (t == 0 ? 2 : 0); i < 16; i += 2)
          vmax = fmaxf(vmax, fmaxf(sacc[t][i], sacc[t][i + 1]));  // v_max3
      vmax = fmaxf(vmax, __shfl_xor(vmax, 32, 64));
      if (!__all(vmax <= m_run + 8.0f)) {  // defer-max (log2 domain, THR=8)
        float m_new = fmaxf(m_run, vmax);
        float alpha = exp2f(m_run - m_new);
        l_run *= alpha;
#pragma unroll
        for (int i = 0; i < 16; ++i) {
          oacc[0][i] *= alpha;
          oacc[1][i] *= alpha;
        }
        m_run = m_new;
      }
      float psum = 0.f;
#pragma unroll
      for (int t = 0; t < 2; ++t)
#pragma unroll
        for (int i = 0; i < 16; ++i) {
          float pv = exp2f(sacc[t][i] - m_run);
          sacc[t][i] = pv;
          psum += pv;
        }
      psum += __shfl_xor(psum, 32, 64);
      l_run += psum;

      // ---- P -> bf16 PV B-fragments: 16 cvt_pk + 8 permlane32_swap ----
      unsigned pword[4][4];
#pragma unroll
      for (int t = 0; t < 2; ++t) {
        unsigned X[4][2];
#pragma unroll
        for (int u2 = 0; u2 < 4; ++u2)
#pragma unroll
          for (int wp = 0; wp < 2; ++wp)
            X[u2][wp] = cvtpk(sacc[t][u2 * 4 + 2 * wp], sacc[t][u2 * 4 + 2 * wp + 1]);
#pragma unroll
        for (int par = 0; par < 2; ++par) {
          const int kb = 2 * t + par;
#pragma unroll
          for (int wp = 0; wp < 2; ++wp) {
            unsigned a = X[2 * par][wp], b2 = X[2 * par + 1][wp];
            pl32swap(a, b2);
            pword[kb][wp] = a;
            pword[kb][wp + 2] = b2;
          }
        }
      }

      // ---- PV ----
      __builtin_amdgcn_s_setprio(1);
#pragma unroll
      for (int kb = 0; kb < 4; ++kb) {
        union { unsigned u[4]; bf16x8 v; } pw;
#pragma unroll
        for (int k2 = 0; k2 < 4; ++k2) pw.u[k2] = pword[kb][k2];
        oacc[0] = MFMA32(vfC[0][kb], pw.v, oacc[0]);
        oacc[1] = MFMA32(vfC[1][kb], pw.v, oacc[1]);
      }
      __builtin_amdgcn_s_setprio(0);
    };

    loadK(0, kfA);
    loadV(0, vfA);
    for (int st = 0; st < S; st += 2) {
      step(st, kfA, vfA, kfB, vfB);
      if (st + 1 < S) step(st + 1, kfB, vfB, kfA, vfA);
    }

    // ---- epilogue ----
    const float linv = 1.f / l_run;
    unsigned short* crow = ctx + ((size_t)(b * 2048 + qw + c5)) * 1024 + h * 64;
#pragma unroll
    for (int dt = 0; dt < 2; ++dt)
#pragma unroll
      for (int u = 0; u < 4; ++u) {
        int d0 = dt * 32 + 8 * u + 4 * hi;
        uint2 o;
        o.x = cvtpk(oacc[dt][4 * u] * linv, oacc[dt][4 * u + 1] * linv);
        o.y = cvtpk(oacc[dt][4 * u + 2] * linv, oacc[dt][4 * u + 3] * linv);
        *(uint2*)(crow + d0) = o;
      }
  };

  pass(P);
  pass(63 - P);
}

// ---------------- launcher ----------------

extern "C" void kernel_launch(void* const* d_in, const int* in_sizes, int n_in,
                              void* d_out, int out_size, void* d_ws, size_t ws_size,
                              hipStream_t stream) {
  (void)in_sizes; (void)n_in; (void)out_size; (void)ws_size;
  const float* x = (const float*)d_in[0];
  const float* Wq = (const float*)d_in[1];
  const float* Wk = (const float*)d_in[2];
  const float* Wv = (const float*)d_in[3];
  const float* Wo = (const float*)d_in[4];
  char* ws = (char*)d_ws;
  const size_t MiB = 1024 * 1024;
  unsigned short* xb  = (unsigned short*)(ws);             // 16 MiB
  unsigned short* WTq = (unsigned short*)(ws + 16 * MiB);  // 2 MiB each
  unsigned short* WTk = (unsigned short*)(ws + 18 * MiB);
  unsigned short* WTv = (unsigned short*)(ws + 20 * MiB);
  unsigned short* WTo = (unsigned short*)(ws + 22 * MiB);
  unsigned short* Qb  = (unsigned short*)(ws + 24 * MiB);  // 16 MiB each
  unsigned short* Kfb = (unsigned short*)(ws + 40 * MiB);
  unsigned short* Vfb = (unsigned short*)(ws + 56 * MiB);
  unsigned short* ctx = (unsigned short*)(ws + 72 * MiB);
  float2* rtab = (float2*)(ws + 88 * MiB);                 // 512 KiB

  conv_x_k<<<8192, 256, 0, stream>>>(x, xb);
  transp_k<<<dim3(16, 16, 4), 256, 0, stream>>>(Wq, Wk, Wv, Wo, WTq, WTk, WTv, WTo);
  rope_k<<<256, 256, 0, stream>>>(rtab);
  gemm_k<0><<<dim3(64, 8), 256, 0, stream>>>(xb, WTq, Qb, rtab);
  gemm_k<1><<<dim3(64, 8), 256, 0, stream>>>(xb, WTk, Kfb, rtab);
  gemm_k<2><<<dim3(64, 8), 256, 0, stream>>>(xb, WTv, Vfb, rtab);
  attn_k<<<512, 256, 0, stream>>>(Qb, Kfb, Vfb, ctx);
  gemm_k<3><<<dim3(64, 8), 256, 0, stream>>>(ctx, WTo, d_out, rtab);
}

// Round 14
// 178.052 us; speedup vs baseline: 1.1076x; 1.0358x over previous
//
#include <hip/hip_runtime.h>

#define DEVFN __device__ __forceinline__

typedef __attribute__((ext_vector_type(8))) short bf16x8;
typedef __attribute__((ext_vector_type(4))) float f32x4;
typedef __attribute__((ext_vector_type(16))) float f32x16;

#define MFMA16(a, b, c) __builtin_amdgcn_mfma_f32_16x16x32_bf16(a, b, c, 0, 0, 0)
#define MFMA32(a, b, c) __builtin_amdgcn_mfma_f32_32x32x16_bf16(a, b, c, 0, 0, 0)

DEVFN unsigned short f2bf(float f) {
  union { float f; unsigned u; } v; v.f = f;
  unsigned r = v.u + 0x7FFFu + ((v.u >> 16) & 1u);
  return (unsigned short)(r >> 16);
}
DEVFN unsigned pack2bf(float a, float b) {
  return (unsigned)f2bf(a) | ((unsigned)f2bf(b) << 16);
}
DEVFN unsigned cvtpk(float lo, float hi) {
  unsigned r;
  asm("v_cvt_pk_bf16_f32 %0, %1, %2" : "=v"(r) : "v"(lo), "v"(hi));
  return r;
}
DEVFN void pl32swap(unsigned& a, unsigned& b) {
  asm("v_permlane32_swap_b32 %0, %1" : "+v"(a), "+v"(b));
}
DEVFN void gll16(const void* g, void* l) {
  __builtin_amdgcn_global_load_lds((__attribute__((address_space(1))) void*)g,
                                   (__attribute__((address_space(3))) void*)l,
                                   16, 0, 0);
}

// ---------------- precompute kernels ----------------

__global__ __launch_bounds__(256) void conv_x_k(const float* __restrict__ x,
                                                unsigned short* __restrict__ xb) {
  int i = (blockIdx.x * 256 + threadIdx.x) * 4;
  float4 v = *(const float4*)(x + i);
  uint2 u;
  u.x = pack2bf(v.x, v.y);
  u.y = pack2bf(v.z, v.w);
  *(uint2*)(xb + i) = u;
}

// WT[n][k] = (bf16) W[k][n], 64x64 tiles through LDS
__global__ __launch_bounds__(256) void transp_k(
    const float* __restrict__ Wq, const float* __restrict__ Wk,
    const float* __restrict__ Wv, const float* __restrict__ Wo,
    unsigned short* __restrict__ Tq, unsigned short* __restrict__ Tk,
    unsigned short* __restrict__ Tv, unsigned short* __restrict__ To) {
  __shared__ unsigned short t[64 * 65];
  int z = blockIdx.z;
  const float* src = (z == 0) ? Wq : (z == 1) ? Wk : (z == 2) ? Wv : Wo;
  unsigned short* dst = (z == 0) ? Tq : (z == 1) ? Tk : (z == 2) ? Tv : To;
  int k0 = blockIdx.x * 64, n0 = blockIdx.y * 64;
  int tid = threadIdx.x;
#pragma unroll
  for (int i = 0; i < 16; ++i) {
    int flat = i * 256 + tid;
    int r = flat >> 6, cc = flat & 63;
    t[cc * 65 + r] = f2bf(src[(size_t)(k0 + r) * 1024 + n0 + cc]);
  }
  __syncthreads();
#pragma unroll
  for (int i = 0; i < 16; ++i) {
    int flat = i * 256 + tid;
    int rr = flat >> 6, cc = flat & 63;
    dst[(size_t)(n0 + rr) * 1024 + k0 + cc] = t[rr * 65 + cc];
  }
}

__global__ __launch_bounds__(256) void rope_k(float2* __restrict__ rtab) {
  int idx = blockIdx.x * 256 + threadIdx.x;  // 2048*32
  int s = idx >> 5, j = idx & 31;
  float freq = expf(-0.28782313714981824f * (float)j);
  float ang = (float)s * freq;
  rtab[idx] = make_float2(sinf(ang), cosf(ang));
}

// ---------------- fused QKV GEMM: 3x C[8192,1024] = xb @ {Wq,Wk,Wv} -------
// blockIdx.y: 0..7 -> Q (RoPE+scale, row-major), 8..15 -> K (RoPE,
// fragment-linear Kf), 16..23 -> V (fragment-linear Vf). Epilogue select is
// block-uniform. Inner loop = m97 structure (gll16 w16 + XOR swizzle).
__global__ __launch_bounds__(256) void gemm_qkv_k(
    const unsigned short* __restrict__ A, const unsigned short* __restrict__ WTq,
    const unsigned short* __restrict__ WTk, const unsigned short* __restrict__ WTv,
    unsigned short* __restrict__ Qb, unsigned short* __restrict__ Kfb,
    unsigned short* __restrict__ Vfb, const float2* __restrict__ rtab) {
  __shared__ unsigned short At[128 * 64];
  __shared__ unsigned short Bt[128 * 64];
  const int tid = threadIdx.x;
  const int w = tid >> 6, lane = tid & 63, g = lane >> 4, c = lane & 15;
  const int wr = w >> 1, wc = w & 1;
  const int which = blockIdx.y >> 3;  // 0=Q 1=K 2=V
  const unsigned short* WT = (which == 0) ? WTq : (which == 1) ? WTk : WTv;
  const int m0 = blockIdx.x * 128, n0 = (blockIdx.y & 7) * 128;

  f32x4 zero = {0.f, 0.f, 0.f, 0.f};
  f32x4 acc[4][4];
#pragma unroll
  for (int i = 0; i < 4; ++i)
#pragma unroll
    for (int j = 0; j < 4; ++j) acc[i][j] = zero;

  for (int k0 = 0; k0 < 1024; k0 += 64) {
#pragma unroll
    for (int p = 0; p < 4; ++p) {
      int i = p * 256 + tid;
      int row = i >> 3, ls = i & 7;
      size_t off = ((size_t)(m0 + row) * 1024 + k0) * 2 + ((ls ^ (row & 7)) << 4);
      gll16((const char*)A + off, (char*)At + p * 4096 + w * 1024);
      size_t offb = ((size_t)(n0 + row) * 1024 + k0) * 2 + ((ls ^ (row & 7)) << 4);
      gll16((const char*)WT + offb, (char*)Bt + p * 4096 + w * 1024);
    }
    __syncthreads();
#pragma unroll
    for (int ks = 0; ks < 2; ++ks) {
      bf16x8 af[4], bfv[4];
#pragma unroll
      for (int am = 0; am < 4; ++am) {
        int row = wr * 64 + am * 16 + c;
        af[am] = *(const bf16x8*)(At + row * 64 + ((((ks << 2) | g) ^ (row & 7)) << 3));
      }
#pragma unroll
      for (int bn = 0; bn < 4; ++bn) {
        int row = wc * 64 + bn * 16 + c;
        bfv[bn] = *(const bf16x8*)(Bt + row * 64 + ((((ks << 2) | g) ^ (row & 7)) << 3));
      }
#pragma unroll
      for (int am = 0; am < 4; ++am)
#pragma unroll
        for (int bn = 0; bn < 4; ++bn)
          acc[am][bn] = MFMA16(af[am], bfv[bn], acc[am][bn]);
    }
    __syncthreads();
  }

  if (which == 0) {
#pragma unroll
    for (int am = 0; am < 4; ++am)
#pragma unroll
      for (int bp = 0; bp < 2; ++bp) {
        int col = n0 + wc * 64 + bp * 16 + c;
        int h = col >> 6, j = col & 63;
#pragma unroll
        for (int r = 0; r < 4; ++r) {
          int row = m0 + wr * 64 + am * 16 + (g << 2) + r;
          int b = row >> 11, s = row & 2047;
          float x1 = acc[am][bp][r], x2 = acc[am][bp + 2][r];
          float2 sc = rtab[s * 32 + j];
          float o1 = (sc.y * x1 - sc.x * x2) * 0.18033688011112042f;
          float o2 = (sc.x * x1 + sc.y * x2) * 0.18033688011112042f;
          size_t base = (((size_t)(b * 16 + h)) * 2048 + s) * 64;
          Qb[base + j] = f2bf(o1);
          Qb[base + 32 + j] = f2bf(o2);
        }
      }
  } else if (which == 1) {
#pragma unroll
    for (int am = 0; am < 4; ++am)
#pragma unroll
      for (int bp = 0; bp < 2; ++bp) {
        int col = n0 + wc * 64 + bp * 16 + c;
        int h = col >> 6, j = col & 63;  // j in [0,32)
        const int kb = j >> 4, hil = (j >> 3) & 1, el = j & 7;
#pragma unroll
        for (int r = 0; r < 4; ++r) {
          int row = m0 + wr * 64 + am * 16 + (g << 2) + r;
          int b = row >> 11, s = row & 2047;
          float x1 = acc[am][bp][r], x2 = acc[am][bp + 2][r];
          float2 sc = rtab[s * 32 + j];
          float o1 = sc.y * x1 - sc.x * x2;
          float o2 = sc.x * x1 + sc.y * x2;
          size_t base = (size_t)(b * 16 + h) * 131072 + (size_t)(s >> 5) * 2048 +
                        (hil * 32 + (s & 31)) * 8 + el;
          Kfb[base + kb * 512] = f2bf(o1);
          Kfb[base + (kb + 2) * 512] = f2bf(o2);
        }
      }
  } else {
#pragma unroll
    for (int am = 0; am < 4; ++am)
#pragma unroll
      for (int bn = 0; bn < 4; ++bn) {
        int col = n0 + wc * 64 + bn * 16 + c;
        int h = col >> 6, d = col & 63;
        int row0 = m0 + wr * 64 + am * 16 + (g << 2);
        int b = row0 >> 11, s0 = row0 & 2047;
        uint2 u;
        u.x = pack2bf(acc[am][bn][0], acc[am][bn][1]);
        u.y = pack2bf(acc[am][bn][2], acc[am][bn][3]);
        size_t off = (size_t)(b * 16 + h) * 131072 + (size_t)(s0 >> 6) * 4096 +
                     ((s0 >> 4) & 3) * 1024 + (d >> 5) * 512 +
                     (((s0 >> 3) & 1) * 32 + (d & 31)) * 8 + (s0 & 7);
        *(uint2*)(Vfb + off) = u;
      }
  }
}

// ---------------- output GEMM: d_out = ctx @ Wo (fp32) ----------------
__global__ __launch_bounds__(256) void gemm_o_k(
    const unsigned short* __restrict__ A, const unsigned short* __restrict__ WT,
    float* __restrict__ outf) {
  __shared__ unsigned short At[128 * 64];
  __shared__ unsigned short Bt[128 * 64];
  const int tid = threadIdx.x;
  const int w = tid >> 6, lane = tid & 63, g = lane >> 4, c = lane & 15;
  const int wr = w >> 1, wc = w & 1;
  const int m0 = blockIdx.x * 128, n0 = blockIdx.y * 128;

  f32x4 zero = {0.f, 0.f, 0.f, 0.f};
  f32x4 acc[4][4];
#pragma unroll
  for (int i = 0; i < 4; ++i)
#pragma unroll
    for (int j = 0; j < 4; ++j) acc[i][j] = zero;

  for (int k0 = 0; k0 < 1024; k0 += 64) {
#pragma unroll
    for (int p = 0; p < 4; ++p) {
      int i = p * 256 + tid;
      int row = i >> 3, ls = i & 7;
      size_t off = ((size_t)(m0 + row) * 1024 + k0) * 2 + ((ls ^ (row & 7)) << 4);
      gll16((const char*)A + off, (char*)At + p * 4096 + w * 1024);
      size_t offb = ((size_t)(n0 + row) * 1024 + k0) * 2 + ((ls ^ (row & 7)) << 4);
      gll16((const char*)WT + offb, (char*)Bt + p * 4096 + w * 1024);
    }
    __syncthreads();
#pragma unroll
    for (int ks = 0; ks < 2; ++ks) {
      bf16x8 af[4], bfv[4];
#pragma unroll
      for (int am = 0; am < 4; ++am) {
        int row = wr * 64 + am * 16 + c;
        af[am] = *(const bf16x8*)(At + row * 64 + ((((ks << 2) | g) ^ (row & 7)) << 3));
      }
#pragma unroll
      for (int bn = 0; bn < 4; ++bn) {
        int row = wc * 64 + bn * 16 + c;
        bfv[bn] = *(const bf16x8*)(Bt + row * 64 + ((((ks << 2) | g) ^ (row & 7)) << 3));
      }
#pragma unroll
      for (int am = 0; am < 4; ++am)
#pragma unroll
        for (int bn = 0; bn < 4; ++bn)
          acc[am][bn] = MFMA16(af[am], bfv[bn], acc[am][bn]);
    }
    __syncthreads();
  }

#pragma unroll
  for (int am = 0; am < 4; ++am)
#pragma unroll
    for (int bn = 0; bn < 4; ++bn)
#pragma unroll
      for (int r = 0; r < 4; ++r)
        outf[(size_t)(m0 + wr * 64 + am * 16 + (g << 2) + r) * 1024 +
             (n0 + wc * 64 + bn * 16 + c)] = acc[am][bn][r];
}

// ---------------- flash attention (causal, barrier-free, frag-linear) ------
// Q: [BH][2048][64] bf16 (pre-scaled 0.125*log2e). Kf/Vf fragment-linear.
// R12 body (validated 80us, FETCH=compulsory). NEW: one unit per wave, 4
// uniform waves/block, 1024 blocks -> 4096 waves = 4/SIMD (R12 was grid-
// limited to 2/SIMD with VALUBusy 60%). Block = (xcd, head-pair, s): waves
// do units {2s,2s+1} x {h0,h1}, all exactly s+1 steps, all phase-aligned
// from st=0 on the same XCD's heads (locality preserved; R10/R11 tripwire).
// Blocks dispatched descending s. VGPR 124 -> 4 waves/SIMD fits (no
// launch_bounds change -- R4 spill lesson).
__global__ __launch_bounds__(256, 2) void attn_k(
    const unsigned short* __restrict__ Q, const unsigned short* __restrict__ Kf,
    const unsigned short* __restrict__ Vf, unsigned short* __restrict__ ctx) {
  const int blk = blockIdx.x;               // 1024 blocks
  const int xcd = blk & 7, j = blk >> 3;    // 8 heads/XCD: K/V L2-resident
  const int hp = j & 3;                     // head-pair within XCD
  const int s = 31 - (j >> 2);              // descending: long blocks first
  const int tid = threadIdx.x;
  const int w = tid >> 6, lane = tid & 63;
  const int hi = lane >> 5, c5 = lane & 31;
  const int bh = xcd * 8 + hp * 2 + (w & 1);
  const int U = 2 * s + (w >> 1);           // this wave's 32-row unit
  const int S = s + 1;                      // kv-steps (uniform in block)
  const int qw = U * 32;

  const unsigned short* Qbh = Q + (size_t)bh * 2048 * 64;
  const unsigned short* Kbh = Kf + (size_t)bh * 131072;
  const unsigned short* Vbh = Vf + (size_t)bh * 131072;
  const int b = bh >> 4, h = bh & 15;

  f32x16 zacc;
#pragma unroll
  for (int i = 0; i < 16; ++i) zacc[i] = 0.f;

  bf16x8 qf[4];
#pragma unroll
  for (int kb = 0; kb < 4; ++kb)
    qf[kb] = *(const bf16x8*)(Qbh + (size_t)(qw + c5) * 64 + kb * 16 + hi * 8);

  f32x16 oacc[2];
  oacc[0] = zacc; oacc[1] = zacc;
  float m_run = -1e30f, l_run = 0.f;

  bf16x8 kfA[2][4], vfA[2][4], kfB[2][4], vfB[2][4];

  auto loadK = [&](int st, bf16x8 (&dst)[2][4]) {
    const unsigned short* kb_ = Kbh + (size_t)st * 4096 + lane * 8;
#pragma unroll
    for (int t = 0; t < 2; ++t)
#pragma unroll
      for (int kb = 0; kb < 4; ++kb)
        dst[t][kb] = *(const bf16x8*)(kb_ + t * 2048 + kb * 512);
  };
  auto loadV = [&](int st, bf16x8 (&dst)[2][4]) {
    const unsigned short* vb_ = Vbh + (size_t)st * 4096 + lane * 8;
#pragma unroll
    for (int kb = 0; kb < 4; ++kb) {
      dst[0][kb] = *(const bf16x8*)(vb_ + kb * 1024);
      dst[1][kb] = *(const bf16x8*)(vb_ + kb * 1024 + 512);
    }
  };

  auto step = [&](int st, bf16x8 (&kfC)[2][4], bf16x8 (&vfC)[2][4],
                  bf16x8 (&kfN)[2][4], bf16x8 (&vfN)[2][4]) {
    f32x16 sacc[2];
    __builtin_amdgcn_s_setprio(1);
#pragma unroll
    for (int t = 0; t < 2; ++t) {
      sacc[t] = MFMA32(kfC[t][0], qf[0], zacc);
#pragma unroll
      for (int kb = 1; kb < 4; ++kb)
        sacc[t] = MFMA32(kfC[t][kb], qf[kb], sacc[t]);
    }
    __builtin_amdgcn_s_setprio(0);

    if (st + 1 < S) {
      loadK(st + 1, kfN);
      loadV(st + 1, vfN);
    }

    if (st == S - 1) {
      const int q = qw + c5;
#pragma unroll
      for (int t = 0; t < 2; ++t) {
        const int kvb = st * 64 + t * 32 + (hi << 2);
#pragma unroll
        for (int i = 0; i < 16; ++i) {
          int kv = kvb + (i & 3) + ((i >> 2) << 3);
          if (kv > q) sacc[t][i] = -1e30f;
        }
      }
    }

    float vmax = fmaxf(sacc[0][0], sacc[0][1]);
#pragma unroll
    for (int t = 0; t < 2; ++t)
#pragma unroll
      for (int i = (t == 0 ? 2 : 0); i < 16; i += 2)
        vmax = fmaxf(vmax, fmaxf(sacc[t][i], sacc[t][i + 1]));  // v_max3
    vmax = fmaxf(vmax, __shfl_xor(vmax, 32, 64));
    if (!__all(vmax <= m_run + 8.0f)) {  // defer-max (log2 domain, THR=8)
      float m_new = fmaxf(m_run, vmax);
      float alpha = exp2f(m_run - m_new);
      l_run *= alpha;
#pragma unroll
      for (int i = 0; i < 16; ++i) {
        oacc[0][i] *= alpha;
        oacc[1][i] *= alpha;
      }
      m_run = m_new;
    }
    float psum = 0.f;
#pragma unroll
    for (int t = 0; t < 2; ++t)
#pragma unroll
      for (int i = 0; i < 16; ++i) {
        float pv = exp2f(sacc[t][i] - m_run);
        sacc[t][i] = pv;
        psum += pv;
      }
    psum += __shfl_xor(psum, 32, 64);
    l_run += psum;

    unsigned pword[4][4];
#pragma unroll
    for (int t = 0; t < 2; ++t) {
      unsigned X[4][2];
#pragma unroll
      for (int u2 = 0; u2 < 4; ++u2)
#pragma unroll
        for (int wp = 0; wp < 2; ++wp)
          X[u2][wp] = cvtpk(sacc[t][u2 * 4 + 2 * wp], sacc[t][u2 * 4 + 2 * wp + 1]);
#pragma unroll
      for (int par = 0; par < 2; ++par) {
        const int kb = 2 * t + par;
#pragma unroll
        for (int wp = 0; wp < 2; ++wp) {
          unsigned a = X[2 * par][wp], b2 = X[2 * par + 1][wp];
          pl32swap(a, b2);
          pword[kb][wp] = a;
          pword[kb][wp + 2] = b2;
        }
      }
    }

    __builtin_amdgcn_s_setprio(1);
#pragma unroll
    for (int kb = 0; kb < 4; ++kb) {
      union { unsigned u[4]; bf16x8 v; } pw;
#pragma unroll
      for (int k2 = 0; k2 < 4; ++k2) pw.u[k2] = pword[kb][k2];
      oacc[0] = MFMA32(vfC[0][kb], pw.v, oacc[0]);
      oacc[1] = MFMA32(vfC[1][kb], pw.v, oacc[1]);
    }
    __builtin_amdgcn_s_setprio(0);
  };

  loadK(0, kfA);
  loadV(0, vfA);
  for (int st = 0; st < S; st += 2) {
    step(st, kfA, vfA, kfB, vfB);
    if (st + 1 < S) step(st + 1, kfB, vfB, kfA, vfA);
  }

  const float linv = 1.f / l_run;
  unsigned short* crow = ctx + ((size_t)(b * 2048 + qw + c5)) * 1024 + h * 64;
#pragma unroll
  for (int dt = 0; dt < 2; ++dt)
#pragma unroll
    for (int u = 0; u < 4; ++u) {
      int d0 = dt * 32 + 8 * u + 4 * hi;
      uint2 o;
      o.x = cvtpk(oacc[dt][4 * u] * linv, oacc[dt][4 * u + 1] * linv);
      o.y = cvtpk(oacc[dt][4 * u + 2] * linv, oacc[dt][4 * u + 3] * linv);
      *(uint2*)(crow + d0) = o;
    }
}

// ---------------- launcher ----------------

extern "C" void kernel_launch(void* const* d_in, const int* in_sizes, int n_in,
                              void* d_out, int out_size, void* d_ws, size_t ws_size,
                              hipStream_t stream) {
  (void)in_sizes; (void)n_in; (void)out_size; (void)ws_size;
  const float* x = (const float*)d_in[0];
  const float* Wq = (const float*)d_in[1];
  const float* Wk = (const float*)d_in[2];
  const float* Wv = (const float*)d_in[3];
  const float* Wo = (const float*)d_in[4];
  char* ws = (char*)d_ws;
  const size_t MiB = 1024 * 1024;
  unsigned short* xb  = (unsigned short*)(ws);             // 16 MiB
  unsigned short* WTq = (unsigned short*)(ws + 16 * MiB);  // 2 MiB each
  unsigned short* WTk = (unsigned short*)(ws + 18 * MiB);
  unsigned short* WTv = (unsigned short*)(ws + 20 * MiB);
  unsigned short* WTo = (unsigned short*)(ws + 22 * MiB);
  unsigned short* Qb  = (unsigned short*)(ws + 24 * MiB);  // 16 MiB each
  unsigned short* Kfb = (unsigned short*)(ws + 40 * MiB);
  unsigned short* Vfb = (unsigned short*)(ws + 56 * MiB);
  unsigned short* ctx = (unsigned short*)(ws + 72 * MiB);
  float2* rtab = (float2*)(ws + 88 * MiB);                 // 512 KiB

  conv_x_k<<<8192, 256, 0, stream>>>(x, xb);
  transp_k<<<dim3(16, 16, 4), 256, 0, stream>>>(Wq, Wk, Wv, Wo, WTq, WTk, WTv, WTo);
  rope_k<<<256, 256, 0, stream>>>(rtab);
  gemm_qkv_k<<<dim3(64, 24), 256, 0, stream>>>(xb, WTq, WTk, WTv, Qb, Kfb, Vfb, rtab);
  attn_k<<<1024, 256, 0, stream>>>(Qb, Kfb, Vfb, ctx);
  gemm_o_k<<<dim3(64, 8), 256, 0, stream>>>(ctx, WTo, (float*)d_out);
}